// Round 4
// baseline (330.173 us; speedup 1.0000x reference)
//
#include <hip/hip_runtime.h>
#include <stdint.h>

#define N_NODES_C 20000
#define N_EDGES_C 320000
#define NUM_RELS_C 16
#define FEAT_C 256

typedef __bf16 bf16_t;
typedef __bf16 bf16x8 __attribute__((ext_vector_type(8)));
typedef __bf16 bf16x4 __attribute__((ext_vector_type(4)));
typedef float f32x4 __attribute__((ext_vector_type(4)));

__device__ __forceinline__ void async_load16(const void* g, void* l) {
  __builtin_amdgcn_global_load_lds(
      (__attribute__((address_space(1))) void*)const_cast<void*>(g),
      (__attribute__((address_space(3))) void*)l, 16, 0, 0);
}

// ---- h fp32 -> bf16 ----
__global__ void cvt_h_kernel(const float* __restrict__ h, bf16_t* __restrict__ hB) {
  int i = (blockIdx.x * blockDim.x + threadIdx.x) * 4;
  float4 v = *(const float4*)(h + i);
  bf16x4 o = { (bf16_t)v.x, (bf16_t)v.y, (bf16_t)v.z, (bf16_t)v.w };
  *(bf16x4*)(hB + i) = o;
}

// ---- W [r][in][out] fp32 -> Wt2 [out][r*256+in] bf16, LDS tile transpose ----
__global__ void cvt_w2_kernel(const float* __restrict__ W, bf16_t* __restrict__ Wt2) {
  __shared__ float t[32][33];
  int r = blockIdx.z, i0 = blockIdx.x << 5, o0 = blockIdx.y << 5;
  int a = threadIdx.x >> 5;
  int b = threadIdx.x & 31;
#pragma unroll
  for (int k = 0; k < 4; ++k) {
    int i = a + (k << 3);
    t[i][b] = W[(r << 16) + ((i0 + i) << 8) + o0 + b];
  }
  __syncthreads();
#pragma unroll
  for (int k = 0; k < 4; ++k) {
    int o = a + (k << 3);
    Wt2[((size_t)(o0 + o) << 12) + (r << 8) + i0 + b] = (bf16_t)t[b][o];
  }
}

// ---- hist over (dst,rel) keys ----
__global__ void hist2_kernel(const int* __restrict__ dst, const int* __restrict__ rel,
                             int* __restrict__ hist2) {
  int e = blockIdx.x * blockDim.x + threadIdx.x;
  if (e < N_EDGES_C) atomicAdd(&hist2[dst[e] * NUM_RELS_C + rel[e]], 1);
}

// ---- per-dst sum of 16 rel counts ----
__global__ void dsum_kernel(const int* __restrict__ hist2, int* __restrict__ dcnt) {
  int d = blockIdx.x * blockDim.x + threadIdx.x;
  if (d >= N_NODES_C) return;
  int s = 0;
#pragma unroll
  for (int r = 0; r < NUM_RELS_C; ++r) s += hist2[d * NUM_RELS_C + r];
  dcnt[d] = s;
}

// ---- single-block exclusive scan of dcnt -> dstart[20001] ----
__global__ void scan_dst_kernel(const int* __restrict__ dcnt, int* __restrict__ dstart) {
  __shared__ int part[256];
  const int CH = 79;
  int t = threadIdx.x;
  int base = t * CH;
  int sum = 0;
  for (int i = 0; i < CH; ++i) {
    int idx = base + i;
    if (idx < N_NODES_C) sum += dcnt[idx];
  }
  part[t] = sum;
  __syncthreads();
  if (t == 0) {
    int run = 0;
    for (int i = 0; i < 256; ++i) { int v = part[i]; part[i] = run; run += v; }
  }
  __syncthreads();
  int run = part[t];
  for (int i = 0; i < CH; ++i) {
    int idx = base + i;
    if (idx < N_NODES_C) {
      dstart[idx] = run;
      run += dcnt[idx];
    }
  }
  if (t == 0) dstart[N_NODES_C] = N_EDGES_C;
}

// ---- per-dst 16-entry prefix: rstart[d*16+r] + cursors ----
__global__ void prefixB_kernel(const int* __restrict__ hist2, const int* __restrict__ dstart,
                               int* __restrict__ rstart, int* __restrict__ rcur) {
  int d = blockIdx.x * blockDim.x + threadIdx.x;
  if (d >= N_NODES_C) return;
  int run = dstart[d];
#pragma unroll
  for (int r = 0; r < NUM_RELS_C; ++r) {
    int idx = d * NUM_RELS_C + r;
    rstart[idx] = run;
    rcur[idx] = run;
    run += hist2[idx];
  }
  if (d == 0) rstart[N_NODES_C * NUM_RELS_C] = N_EDGES_C;
}

// ---- bucket edges sorted by (dst,rel); pack (norm_bf16<<16 | src) in 4 B ----
__global__ void bucket2_kernel(const int* __restrict__ dst, const int* __restrict__ src,
                               const int* __restrict__ rel, const float* __restrict__ norm,
                               int* __restrict__ rcur, uint32_t* __restrict__ bkt) {
  int e = blockIdx.x * blockDim.x + threadIdx.x;
  if (e < N_EDGES_C) {
    int pos = atomicAdd(&rcur[dst[e] * NUM_RELS_C + rel[e]], 1);
    bf16_t nb = (bf16_t)norm[e];
    uint16_t nbits = __builtin_bit_cast(uint16_t, nb);
    bkt[pos] = (uint32_t)src[e] | ((uint32_t)nbits << 16);
  }
}

// ---- G build: one wave per dst, register accumulation over rel-runs.
// lane covers features 4l..4l+3 (bf16x4 = 8B/lane, 512B/row coalesced). ----
__global__ __launch_bounds__(256) void gbuild_kernel(
    const bf16_t* __restrict__ hB, const int* __restrict__ rstart,
    const uint32_t* __restrict__ bkt, bf16_t* __restrict__ G) {
  int d = blockIdx.x * 4 + (threadIdx.x >> 6);
  int lane = threadIdx.x & 63;
  bf16_t* g = G + ((size_t)d << 12) + (lane << 2);
  const int* rs = rstart + d * NUM_RELS_C;
#pragma unroll 4
  for (int r = 0; r < NUM_RELS_C; ++r) {
    int p0 = rs[r], p1 = rs[r + 1];
    f32x4 acc = {0.f, 0.f, 0.f, 0.f};
    for (int p = p0; p < p1; ++p) {
      uint32_t w = bkt[p];
      int s = w & 0xFFFF;
      float nm = (float)__builtin_bit_cast(bf16_t, (uint16_t)(w >> 16));
      bf16x4 v = *(const bf16x4*)(hB + ((size_t)s << 8) + (lane << 2));
      acc[0] += nm * (float)v[0];
      acc[1] += nm * (float)v[1];
      acc[2] += nm * (float)v[2];
      acc[3] += nm * (float)v[3];
    }
    bf16x4 o = { (bf16_t)acc[0], (bf16_t)acc[1], (bf16_t)acc[2], (bf16_t)acc[3] };
    *(bf16x4*)(g + (r << 8)) = o;
  }
}

// ---- GEMM: out[20000,256] = G[20000,4096] @ Wt2^T, split-K=2, atomic epilogue.
// LDS = two [128][64B] half-K sub-tiles per operand (R2's verified 0-conflict
// layout: row stride 64B=16 banks, chunk swizzle pq ^ ((row>>1)&3)). ----
__global__ __launch_bounds__(256) void gemm_kernel(
    const bf16_t* __restrict__ G, const bf16_t* __restrict__ Wt2,
    float* __restrict__ out) {
  int m0 = blockIdx.x * 128;
  int n0 = blockIdx.y * 128;
  int kz = blockIdx.z;
  __shared__ bf16_t Asm[128 * 64];   // [inner:2][row:128][32 elem] = 16 KB
  __shared__ bf16_t Bsm[128 * 64];
  int tid = threadIdx.x;

  const char* gA[4];
  const char* gB[4];
  char* lA[4];
  char* lB[4];
#pragma unroll
  for (int l = 0; l < 4; ++l) {
    int idx = l * 256 + tid;          // 16B-chunk index 0..1023
    int inner = idx >> 9;             // half-K sub-tile
    int row = (idx >> 2) & 127;
    int pq = idx & 3;
    int lc = pq ^ ((row >> 1) & 3);   // logical 16B chunk within 64B half-slab
    int koff = inner * 64 + lc * 16;  // byte offset within 128B k-slab
    int grA = m0 + row; if (grA > N_NODES_C - 1) grA = N_NODES_C - 1;
    gA[l] = (const char*)G + ((size_t)grA << 13) + koff;
    gB[l] = (const char*)Wt2 + ((size_t)(n0 + row) << 13) + koff;
    lA[l] = (char*)Asm + idx * 16;
    lB[l] = (char*)Bsm + idx * 16;
  }

  int lane = tid & 63;
  int lq = lane >> 4;
  int lr = lane & 15;
  int wave = tid >> 6;
  int wm = (wave >> 1) * 64;
  int wn = (wave & 1) * 64;
  int cq = (lq ^ ((lr >> 1) & 3)) * 8;

  f32x4 acc[4][4] = {};

  for (int t = 0; t < 32; ++t) {
    int kb = (kz * 32 + t) * 128;   // byte offset of this 64-elem k-slab
#pragma unroll
    for (int l = 0; l < 4; ++l) async_load16(gA[l] + kb, lA[l]);
#pragma unroll
    for (int l = 0; l < 4; ++l) async_load16(gB[l] + kb, lB[l]);
    __syncthreads();
    bf16x8 af[2][4], bfr[2][4];
#pragma unroll
    for (int inner = 0; inner < 2; ++inner)
#pragma unroll
      for (int mt = 0; mt < 4; ++mt) {
        int row = wm + mt * 16 + lr;
        af[inner][mt] = *(const bf16x8*)&Asm[inner * 4096 + row * 32 + cq];
      }
#pragma unroll
    for (int inner = 0; inner < 2; ++inner)
#pragma unroll
      for (int nt = 0; nt < 4; ++nt) {
        int row = wn + nt * 16 + lr;
        bfr[inner][nt] = *(const bf16x8*)&Bsm[inner * 4096 + row * 32 + cq];
      }
#pragma unroll
    for (int inner = 0; inner < 2; ++inner)
#pragma unroll
      for (int mt = 0; mt < 4; ++mt)
#pragma unroll
        for (int nt = 0; nt < 4; ++nt)
          acc[mt][nt] = __builtin_amdgcn_mfma_f32_16x16x32_bf16(af[inner][mt], bfr[inner][nt], acc[mt][nt], 0, 0, 0);
    __syncthreads();
  }

  // Epilogue: C/D map col=lane&15, row=quad*4+reg. atomicAdd (split-K=2).
#pragma unroll
  for (int mt = 0; mt < 4; ++mt) {
#pragma unroll
    for (int rg = 0; rg < 4; ++rg) {
      int row = m0 + wm + mt * 16 + lq * 4 + rg;
      if (row < N_NODES_C) {
#pragma unroll
        for (int nt = 0; nt < 4; ++nt)
          atomicAdd(&out[((size_t)row << 8) + n0 + wn + nt * 16 + lr], acc[mt][nt][rg]);
      }
    }
  }
}

extern "C" void kernel_launch(void* const* d_in, const int* in_sizes, int n_in,
                              void* d_out, int out_size, void* d_ws, size_t ws_size,
                              hipStream_t stream) {
  const float* h    = (const float*)d_in[0];
  const float* W    = (const float*)d_in[1];
  const float* norm = (const float*)d_in[2];
  const int*   src  = (const int*)d_in[3];
  const int*   dst  = (const int*)d_in[4];
  const int*   rel  = (const int*)d_in[5];
  float* out = (float*)d_out;

  char* ws = (char*)d_ws;
  bf16_t* G    = (bf16_t*)ws;                    // 163,840,000 B
  // transient aliases inside G (all dead before gbuild writes G):
  int* hist2   = (int*)ws;                       // 1,280,000 B
  int* dcnt    = (int*)(ws + 1280000);           //    80,000 B
  int* dstart  = (int*)(ws + 1360000);           //    80,004 B
  int* rcur    = (int*)(ws + 1440016);           // 1,280,000 B
  // persistent (alive during gbuild/gemm):
  bf16_t* Wt2  = (bf16_t*)(ws + 163840000);      //  2,097,152 B
  bf16_t* hB   = (bf16_t*)(ws + 165937152);      // 10,240,000 B
  int* rstart  = (int*)(ws + 176177152);         //  1,280,064 B (320001 ints)
  uint32_t* bkt = (uint32_t*)(ws + 177457216);   //  1,280,000 B  -> end 178,737,216

  hipMemsetAsync(hist2, 0, 1280000, stream);
  hipMemsetAsync(out, 0, (size_t)out_size * sizeof(float), stream);
  cvt_h_kernel<<<5000, 256, 0, stream>>>(h, hB);
  cvt_w2_kernel<<<dim3(8, 8, NUM_RELS_C), 256, 0, stream>>>(W, Wt2);
  hist2_kernel<<<1250, 256, 0, stream>>>(dst, rel, hist2);
  dsum_kernel<<<79, 256, 0, stream>>>(hist2, dcnt);
  scan_dst_kernel<<<1, 256, 0, stream>>>(dcnt, dstart);
  prefixB_kernel<<<79, 256, 0, stream>>>(hist2, dstart, rstart, rcur);
  bucket2_kernel<<<1250, 256, 0, stream>>>(dst, src, rel, norm, rcur, bkt);
  gbuild_kernel<<<5000, 256, 0, stream>>>(hB, rstart, bkt, G);
  gemm_kernel<<<dim3(157, 2, 2), 256, 0, stream>>>(G, Wt2, out);
}

// Round 5
// 323.612 us; speedup vs baseline: 1.0203x; 1.0203x over previous
//
#include <hip/hip_runtime.h>
#include <stdint.h>

#define N_NODES_C 20000
#define N_EDGES_C 320000
#define NUM_RELS_C 16
#define FEAT_C 256

typedef __bf16 bf16_t;
typedef __bf16 bf16x8 __attribute__((ext_vector_type(8)));
typedef __bf16 bf16x4 __attribute__((ext_vector_type(4)));
typedef float f32x4 __attribute__((ext_vector_type(4)));

__device__ __forceinline__ void async_load16(const void* g, void* l) {
  __builtin_amdgcn_global_load_lds(
      (__attribute__((address_space(1))) void*)const_cast<void*>(g),
      (__attribute__((address_space(3))) void*)l, 16, 0, 0);
}

// ---- W [r][in][out] fp32 -> Wt2 [out][r*256+in] bf16, LDS tile transpose ----
__global__ void cvt_w2_kernel(const float* __restrict__ W, bf16_t* __restrict__ Wt2) {
  __shared__ float t[32][33];
  int r = blockIdx.z, i0 = blockIdx.x << 5, o0 = blockIdx.y << 5;
  int a = threadIdx.x >> 5;
  int b = threadIdx.x & 31;
#pragma unroll
  for (int k = 0; k < 4; ++k) {
    int i = a + (k << 3);
    t[i][b] = W[(r << 16) + ((i0 + i) << 8) + o0 + b];
  }
  __syncthreads();
#pragma unroll
  for (int k = 0; k < 4; ++k) {
    int o = a + (k << 3);
    Wt2[((size_t)(o0 + o) << 12) + (r << 8) + i0 + b] = (bf16_t)t[b][o];
  }
}

// ---- hist over (dst,rel) keys ----
__global__ void hist2_kernel(const int* __restrict__ dst, const int* __restrict__ rel,
                             int* __restrict__ hist2) {
  int e = blockIdx.x * blockDim.x + threadIdx.x;
  if (e < N_EDGES_C) atomicAdd(&hist2[dst[e] * NUM_RELS_C + rel[e]], 1);
}

// ---- per-dst sum of 16 rel counts ----
__global__ void dsum_kernel(const int* __restrict__ hist2, int* __restrict__ dcnt) {
  int d = blockIdx.x * blockDim.x + threadIdx.x;
  if (d >= N_NODES_C) return;
  int s = 0;
#pragma unroll
  for (int r = 0; r < NUM_RELS_C; ++r) s += hist2[d * NUM_RELS_C + r];
  dcnt[d] = s;
}

// ---- single-block exclusive scan of dcnt -> dstart[20001] ----
__global__ void scan_dst_kernel(const int* __restrict__ dcnt, int* __restrict__ dstart) {
  __shared__ int part[256];
  const int CH = 79;
  int t = threadIdx.x;
  int base = t * CH;
  int sum = 0;
  for (int i = 0; i < CH; ++i) {
    int idx = base + i;
    if (idx < N_NODES_C) sum += dcnt[idx];
  }
  part[t] = sum;
  __syncthreads();
  if (t == 0) {
    int run = 0;
    for (int i = 0; i < 256; ++i) { int v = part[i]; part[i] = run; run += v; }
  }
  __syncthreads();
  int run = part[t];
  for (int i = 0; i < CH; ++i) {
    int idx = base + i;
    if (idx < N_NODES_C) {
      dstart[idx] = run;
      run += dcnt[idx];
    }
  }
  if (t == 0) dstart[N_NODES_C] = N_EDGES_C;
}

// ---- per-dst 16-entry prefix: rstart[d*16+r] + cursors ----
__global__ void prefixB_kernel(const int* __restrict__ hist2, const int* __restrict__ dstart,
                               int* __restrict__ rstart, int* __restrict__ rcur) {
  int d = blockIdx.x * blockDim.x + threadIdx.x;
  if (d >= N_NODES_C) return;
  int run = dstart[d];
#pragma unroll
  for (int r = 0; r < NUM_RELS_C; ++r) {
    int idx = d * NUM_RELS_C + r;
    rstart[idx] = run;
    rcur[idx] = run;
    run += hist2[idx];
  }
  if (d == 0) rstart[N_NODES_C * NUM_RELS_C] = N_EDGES_C;
}

// ---- bucket edges sorted by (dst,rel); pack (norm_bf16<<16 | src) in 4 B ----
__global__ void bucket2_kernel(const int* __restrict__ dst, const int* __restrict__ src,
                               const int* __restrict__ rel, const float* __restrict__ norm,
                               int* __restrict__ rcur, uint32_t* __restrict__ bkt) {
  int e = blockIdx.x * blockDim.x + threadIdx.x;
  if (e < N_EDGES_C) {
    int pos = atomicAdd(&rcur[dst[e] * NUM_RELS_C + rel[e]], 1);
    bf16_t nb = (bf16_t)norm[e];
    uint16_t nbits = __builtin_bit_cast(uint16_t, nb);
    bkt[pos] = (uint32_t)src[e] | ((uint32_t)nbits << 16);
  }
}

// ---- G build: one wave per dst, register accumulation over rel-runs.
// Reads h fp32 directly (L3-resident, 20 MB): lane covers feats 4l..4l+3. ----
__global__ __launch_bounds__(256) void gbuild_kernel(
    const float* __restrict__ h, const int* __restrict__ rstart,
    const uint32_t* __restrict__ bkt, bf16_t* __restrict__ G) {
  int d = blockIdx.x * 4 + (threadIdx.x >> 6);
  int lane = threadIdx.x & 63;
  bf16_t* g = G + ((size_t)d << 12) + (lane << 2);
  const int* rs = rstart + d * NUM_RELS_C;
#pragma unroll 4
  for (int r = 0; r < NUM_RELS_C; ++r) {
    int p0 = rs[r], p1 = rs[r + 1];
    f32x4 acc = {0.f, 0.f, 0.f, 0.f};
    for (int p = p0; p < p1; ++p) {
      uint32_t w = bkt[p];
      int s = w & 0xFFFF;
      float nm = (float)__builtin_bit_cast(bf16_t, (uint16_t)(w >> 16));
      float4 v = *(const float4*)(h + ((size_t)s << 8) + (lane << 2));
      acc[0] += nm * v.x;
      acc[1] += nm * v.y;
      acc[2] += nm * v.z;
      acc[3] += nm * v.w;
    }
    bf16x4 o = { (bf16_t)acc[0], (bf16_t)acc[1], (bf16_t)acc[2], (bf16_t)acc[3] };
    *(bf16x4*)(g + (r << 8)) = o;
  }
}

// ---- GEMM: out[20000,256] = G[20000,4096] @ Wt2^T. 128x128 tile, BK=64,
// DOUBLE-BUFFERED async staging: slab t+1 issued right after the barrier,
// so its ~900-cyc HBM latency overlaps slab t's MFMA+ds_read phase.
// LDS layout per slab = two [128][64B] half-K sub-tiles per operand
// (R4's verified 0-conflict swizzle). Direct stores, no split-K. ----
__global__ __launch_bounds__(256) void gemm_kernel(
    const bf16_t* __restrict__ G, const bf16_t* __restrict__ Wt2,
    float* __restrict__ out) {
  int m0 = blockIdx.x * 128;
  int n0 = blockIdx.y * 128;
  __shared__ bf16_t Asm[2][128 * 64];   // 2 x 16 KB
  __shared__ bf16_t Bsm[2][128 * 64];   // 2 x 16 KB
  int tid = threadIdx.x;

  const char* gA[4];
  const char* gB[4];
  uint32_t loff[4];
#pragma unroll
  for (int l = 0; l < 4; ++l) {
    int idx = l * 256 + tid;          // 16B-chunk index 0..1023
    int inner = idx >> 9;             // half-K sub-tile
    int row = (idx >> 2) & 127;
    int pq = idx & 3;
    int lc = pq ^ ((row >> 1) & 3);   // swizzled 16B chunk within 64B half-slab
    int koff = inner * 64 + lc * 16;  // byte offset within 128B k-slab
    int grA = m0 + row; if (grA > N_NODES_C - 1) grA = N_NODES_C - 1;
    gA[l] = (const char*)G + ((size_t)grA << 13) + koff;
    gB[l] = (const char*)Wt2 + ((size_t)(n0 + row) << 13) + koff;
    loff[l] = idx * 16;
  }

  int lane = tid & 63;
  int lq = lane >> 4;
  int lr = lane & 15;
  int wave = tid >> 6;
  int wm = (wave >> 1) * 64;
  int wn = (wave & 1) * 64;
  int cq = (lq ^ ((lr >> 1) & 3)) * 8;

  f32x4 acc[4][4] = {};

  // preload slab 0 into buffer 0
#pragma unroll
  for (int l = 0; l < 4; ++l) async_load16(gA[l], (char*)Asm[0] + loff[l]);
#pragma unroll
  for (int l = 0; l < 4; ++l) async_load16(gB[l], (char*)Bsm[0] + loff[l]);

  for (int t = 0; t < 64; ++t) {
    __syncthreads();   // drains slab t's loads (issued one full compute ago)
    if (t < 63) {
      int kb = (t + 1) * 128;
      int nb = (t + 1) & 1;
#pragma unroll
      for (int l = 0; l < 4; ++l) async_load16(gA[l] + kb, (char*)Asm[nb] + loff[l]);
#pragma unroll
      for (int l = 0; l < 4; ++l) async_load16(gB[l] + kb, (char*)Bsm[nb] + loff[l]);
    }
    const bf16_t* Ab = Asm[t & 1];
    const bf16_t* Bb = Bsm[t & 1];
    bf16x8 af[2][4], bfr[2][4];
#pragma unroll
    for (int inner = 0; inner < 2; ++inner)
#pragma unroll
      for (int mt = 0; mt < 4; ++mt) {
        int row = wm + mt * 16 + lr;
        af[inner][mt] = *(const bf16x8*)&Ab[inner * 4096 + row * 32 + cq];
      }
#pragma unroll
    for (int inner = 0; inner < 2; ++inner)
#pragma unroll
      for (int nt = 0; nt < 4; ++nt) {
        int row = wn + nt * 16 + lr;
        bfr[inner][nt] = *(const bf16x8*)&Bb[inner * 4096 + row * 32 + cq];
      }
#pragma unroll
    for (int inner = 0; inner < 2; ++inner)
#pragma unroll
      for (int mt = 0; mt < 4; ++mt)
#pragma unroll
        for (int nt = 0; nt < 4; ++nt)
          acc[mt][nt] = __builtin_amdgcn_mfma_f32_16x16x32_bf16(af[inner][mt], bfr[inner][nt], acc[mt][nt], 0, 0, 0);
  }

  // Epilogue: C/D map col=lane&15, row=quad*4+reg. Direct stores (each out row
  // owned by exactly one block -> no memset, no atomics).
#pragma unroll
  for (int mt = 0; mt < 4; ++mt) {
#pragma unroll
    for (int rg = 0; rg < 4; ++rg) {
      int row = m0 + wm + mt * 16 + lq * 4 + rg;
      if (row < N_NODES_C) {
#pragma unroll
        for (int nt = 0; nt < 4; ++nt)
          out[((size_t)row << 8) + n0 + wn + nt * 16 + lr] = acc[mt][nt][rg];
      }
    }
  }
}

extern "C" void kernel_launch(void* const* d_in, const int* in_sizes, int n_in,
                              void* d_out, int out_size, void* d_ws, size_t ws_size,
                              hipStream_t stream) {
  const float* h    = (const float*)d_in[0];
  const float* W    = (const float*)d_in[1];
  const float* norm = (const float*)d_in[2];
  const int*   src  = (const int*)d_in[3];
  const int*   dst  = (const int*)d_in[4];
  const int*   rel  = (const int*)d_in[5];
  float* out = (float*)d_out;

  char* ws = (char*)d_ws;
  bf16_t* G    = (bf16_t*)ws;                    // 163,840,000 B
  // transient aliases inside G (all dead before gbuild writes G):
  int* hist2   = (int*)ws;                       // 1,280,000 B
  int* dcnt    = (int*)(ws + 1280000);           //    80,000 B
  int* dstart  = (int*)(ws + 1360000);           //    80,004 B
  int* rcur    = (int*)(ws + 1440016);           // 1,280,000 B
  // persistent (alive during gbuild/gemm):
  bf16_t* Wt2  = (bf16_t*)(ws + 163840000);      //  2,097,152 B
  int* rstart  = (int*)(ws + 165937152);         //  1,280,064 B (320001 ints)
  uint32_t* bkt = (uint32_t*)(ws + 167217216);   //  1,280,000 B -> end 168,497,216

  hipMemsetAsync(hist2, 0, 1280000, stream);
  cvt_w2_kernel<<<dim3(8, 8, NUM_RELS_C), 256, 0, stream>>>(W, Wt2);
  hist2_kernel<<<1250, 256, 0, stream>>>(dst, rel, hist2);
  dsum_kernel<<<79, 256, 0, stream>>>(hist2, dcnt);
  scan_dst_kernel<<<1, 256, 0, stream>>>(dcnt, dstart);
  prefixB_kernel<<<79, 256, 0, stream>>>(hist2, dstart, rstart, rcur);
  bucket2_kernel<<<1250, 256, 0, stream>>>(dst, src, rel, norm, rcur, bkt);
  gbuild_kernel<<<5000, 256, 0, stream>>>(h, rstart, bkt, G);
  gemm_kernel<<<dim3(157, 2), 256, 0, stream>>>(G, Wt2, out);
}